// Round 4
// baseline (479.647 us; speedup 1.0000x reference)
//
#include <hip/hip_runtime.h>
#include <hip/hip_bf16.h>
#include <math.h>

#define NN   10000
#define EE   160000
#define CC   128
#define RBFD 20
#define HIDD 32
#define WND  384
#define MROW 1152   // 9*128 accumulator row
#define RSTR 76     // sorted row stride (floats): 64 h | 9 y | 3 pad
#define RSTR4 19    // float4 chunks per row
#define TILE 8      // rows per gather tile
#define GW   8      // waves per gather block
#define WCOLS 36    // padded column stride (floats) in LDS weight bank
#define WMATF (WND * WCOLS)   // 13824 floats per matrix in LDS
#define TILEF (TILE * RSTR)   // 608 floats per tile buffer

// Static device buffers (fully rewritten each call).
__device__ __align__(16) float g_row[((size_t)EE + 2 * TILE) * RSTR]; // 48.7 MB
__device__ int   g_dst[EE + 2 * TILE];
__device__ __align__(16) float g_accu[(size_t)NN * MROW];             // 46 MB
__device__ int g_deg[NN];
__device__ int g_offs[NN + 1];
__device__ int g_rel[EE];

__device__ __forceinline__ float silu_f(float x) { return x / (1.f + __expf(-x)); }

__global__ __launch_bounds__(256) void zero_deg_kernel()
{
    int i = blockIdx.x * 256 + threadIdx.x;
    if (i < NN) g_deg[i] = 0;
}

__global__ __launch_bounds__(256) void hist_kernel(const int* __restrict__ edge_index)
{
    int e = blockIdx.x * 256 + threadIdx.x;
    if (e < EE) g_rel[e] = atomicAdd(&g_deg[edge_index[e]], 1);
}

__global__ __launch_bounds__(1024) void scan_kernel()
{
    __shared__ int s[1024];
    __shared__ int carry;
    if (threadIdx.x == 0) { carry = 0; g_offs[0] = 0; }
    __syncthreads();
    for (int base = 0; base < NN; base += 1024) {
        int i = base + threadIdx.x;
        int v = (i < NN) ? g_deg[i] : 0;
        s[threadIdx.x] = v;
        __syncthreads();
        for (int off = 1; off < 1024; off <<= 1) {
            int t = (threadIdx.x >= off) ? s[threadIdx.x - off] : 0;
            __syncthreads();
            s[threadIdx.x] += t;
            __syncthreads();
        }
        if (i < NN) g_offs[i + 1] = carry + s[threadIdx.x];
        __syncthreads();
        if (threadIdx.x == 0) carry += s[1023];
        __syncthreads();
    }
}

// Per-edge MLP1; writes combined row [64 h | 9 y | pad] to sorted position
// via per-wave LDS transpose -> coalesced 304B row stores.
__global__ __launch_bounds__(128) void mlp1_kernel(
    const float* __restrict__ node_feat,
    const float* __restrict__ edge_attr,
    const float* __restrict__ edge_rsh,
    const int*   __restrict__ edge_index,
    const float* __restrict__ Ws1, const float* __restrict__ bs1,
    const float* __restrict__ Wr1, const float* __restrict__ br1)
{
    __shared__ float sH[2][64][RSTR + 1];   // +1: 77 is odd -> conflict-free both ways
    __shared__ int   sRow[2][64];

    int e = blockIdx.x * 128 + threadIdx.x;   // grid exact: EE/128
    int w = threadIdx.x >> 6, l = threadIdx.x & 63;

    int s = edge_index[e];
    int t = edge_index[EE + e];
    const float* xi = node_feat + (size_t)s * CC;
    const float* xj = node_feat + (size_t)t * CC;

    float hs[HIDD];
    #pragma unroll
    for (int j = 0; j < HIDD; ++j) hs[j] = bs1[j];
    #pragma unroll 1
    for (int k4 = 0; k4 < CC / 4; ++k4) {
        float4 a = reinterpret_cast<const float4*>(xi)[k4];
        const float* wp = Ws1 + (4 * k4) * HIDD;
        #pragma unroll
        for (int j = 0; j < HIDD; ++j) {
            hs[j] = fmaf(a.x, wp[j],            hs[j]);
            hs[j] = fmaf(a.y, wp[HIDD + j],     hs[j]);
            hs[j] = fmaf(a.z, wp[2 * HIDD + j], hs[j]);
            hs[j] = fmaf(a.w, wp[3 * HIDD + j], hs[j]);
        }
    }
    #pragma unroll 1
    for (int k4 = 0; k4 < CC / 4; ++k4) {
        float4 a = reinterpret_cast<const float4*>(xj)[k4];
        const float* wp = Ws1 + (CC + 4 * k4) * HIDD;
        #pragma unroll
        for (int j = 0; j < HIDD; ++j) {
            hs[j] = fmaf(a.x, wp[j],            hs[j]);
            hs[j] = fmaf(a.y, wp[HIDD + j],     hs[j]);
            hs[j] = fmaf(a.z, wp[2 * HIDD + j], hs[j]);
            hs[j] = fmaf(a.w, wp[3 * HIDD + j], hs[j]);
        }
    }

    float hr[HIDD];
    #pragma unroll
    for (int j = 0; j < HIDD; ++j) hr[j] = br1[j];
    #pragma unroll 1
    for (int k4 = 0; k4 < RBFD / 4; ++k4) {
        float4 a = reinterpret_cast<const float4*>(edge_attr + (size_t)e * RBFD)[k4];
        const float* wp = Wr1 + (4 * k4) * HIDD;
        #pragma unroll
        for (int j = 0; j < HIDD; ++j) {
            hr[j] = fmaf(a.x, wp[j],            hr[j]);
            hr[j] = fmaf(a.y, wp[HIDD + j],     hr[j]);
            hr[j] = fmaf(a.z, wp[2 * HIDD + j], hr[j]);
            hr[j] = fmaf(a.w, wp[3 * HIDD + j], hr[j]);
        }
    }

    int row = g_offs[s] + g_rel[e];
    g_dst[row] = t;

    sRow[w][l] = row;
    #pragma unroll
    for (int j = 0; j < HIDD; ++j) {
        sH[w][l][j]        = silu_f(hs[j]);
        sH[w][l][HIDD + j] = silu_f(hr[j]);
    }
    #pragma unroll
    for (int i = 0; i < 9; ++i) sH[w][l][64 + i] = edge_rsh[(size_t)e * 9 + i];
    __syncthreads();
    #pragma unroll 4
    for (int r = 0; r < 64; ++r) {
        size_t rw = (size_t)sRow[w][r];
        g_row[rw * RSTR + l] = sH[w][r][l];
        if (l < 12) g_row[rw * RSTR + 64 + l] = sH[w][r][64 + l];
    }
}

// ---------------- gather3: wave-per-node, weights in LDS ----------------

__device__ __forceinline__ float dot4(float4 a, float4 b, float c)
{
    c = fmaf(a.x, b.x, c); c = fmaf(a.y, b.y, c);
    c = fmaf(a.z, b.z, c); c = fmaf(a.w, b.w, c);
    return c;
}

__device__ __forceinline__ void tile_load(int t0, int end, int l,
    const float* __restrict__ nf, float4 (&raw)[3], float (&xj)[TILE][2])
{
    const float4* gr = reinterpret_cast<const float4*>(g_row) + (size_t)t0 * RSTR4;
    const float4 z = make_float4(0.f, 0.f, 0.f, 0.f);
    #pragma unroll
    for (int u = 0; u < 3; ++u) {
        int k = l + 64 * u;   // chunk index within tile (152 total)
        bool ok = (k < TILE * RSTR4) && (t0 + k / RSTR4 < end);
        raw[u] = ok ? gr[k] : z;
    }
    #pragma unroll
    for (int rr = 0; rr < TILE; ++rr) {
        int dn = (t0 + rr < end) ? g_dst[t0 + rr] : 0;
        xj[rr][0] = nf[(size_t)dn * CC + l];
        xj[rr][1] = nf[(size_t)dn * CC + 64 + l];
    }
}

__device__ __forceinline__ void tile_store_lds(float* tb, int l, const float4 (&raw)[3])
{
    float4* t4 = reinterpret_cast<float4*>(tb);
    #pragma unroll
    for (int u = 0; u < 3; ++u) {
        int k = l + 64 * u;
        if (k < TILE * RSTR4) t4[k] = raw[u];
    }
}

__device__ __forceinline__ void pair_rows(const float* rowA,
    const float* const (&cS)[3][2], const float* const (&cR)[3][2],
    const float (&bS)[3][2], const float (&bR)[3][2],
    float xa0, float xa1, float xb0, float xb1, float (&acc)[9][2])
{
    const float* rowB = rowA + RSTR;
    float asA[3][2], arA[3][2], asB[3][2], arB[3][2];
    #pragma unroll
    for (int m = 0; m < 3; ++m)
        #pragma unroll
        for (int q = 0; q < 2; ++q) {
            asA[m][q] = bS[m][q]; asB[m][q] = bS[m][q];
            arA[m][q] = bR[m][q]; arB[m][q] = bR[m][q];
        }
    #pragma unroll 2
    for (int j4 = 0; j4 < 8; ++j4) {
        float4 haS = *reinterpret_cast<const float4*>(rowA + 4 * j4);
        float4 haR = *reinterpret_cast<const float4*>(rowA + 32 + 4 * j4);
        float4 hbS = *reinterpret_cast<const float4*>(rowB + 4 * j4);
        float4 hbR = *reinterpret_cast<const float4*>(rowB + 32 + 4 * j4);
        #pragma unroll
        for (int m = 0; m < 3; ++m)
            #pragma unroll
            for (int q = 0; q < 2; ++q) {
                float4 w4 = *reinterpret_cast<const float4*>(cS[m][q] + 4 * j4);
                asA[m][q] = dot4(haS, w4, asA[m][q]);
                asB[m][q] = dot4(hbS, w4, asB[m][q]);
                float4 v4 = *reinterpret_cast<const float4*>(cR[m][q] + 4 * j4);
                arA[m][q] = dot4(haR, v4, arA[m][q]);
                arB[m][q] = dot4(hbR, v4, arB[m][q]);
            }
    }
    const float* yA = rowA + 64;
    const float* yB = rowB + 64;
    #pragma unroll
    for (int q = 0; q < 2; ++q) {
        float xa = q ? xa1 : xa0, xb = q ? xb1 : xb0;
        float wa0 = asA[0][q] * arA[0][q] * xa;
        float wa1 = asA[1][q] * arA[1][q] * xa;
        float wa2 = asA[2][q] * arA[2][q] * xa;
        float wb0 = asB[0][q] * arB[0][q] * xb;
        float wb1 = asB[1][q] * arB[1][q] * xb;
        float wb2 = asB[2][q] * arB[2][q] * xb;
        acc[0][q] = fmaf(wa0, yA[0], acc[0][q]);
        acc[0][q] = fmaf(wb0, yB[0], acc[0][q]);
        #pragma unroll
        for (int k = 0; k < 3; ++k) {
            acc[1 + k][q] = fmaf(wa1, yA[1 + k], acc[1 + k][q]);
            acc[1 + k][q] = fmaf(wb1, yB[1 + k], acc[1 + k][q]);
        }
        #pragma unroll
        for (int k = 0; k < 5; ++k) {
            acc[4 + k][q] = fmaf(wa2, yA[4 + k], acc[4 + k][q]);
            acc[4 + k][q] = fmaf(wb2, yB[4 + k], acc[4 + k][q]);
        }
    }
}

__device__ __forceinline__ void tile_compute(const float* tb, int nr,
    const float* const (&cS)[3][2], const float* const (&cR)[3][2],
    const float (&bS)[3][2], const float (&bR)[3][2],
    const float (&xj)[TILE][2], float (&acc)[9][2])
{
    int npairs = (nr + 1) >> 1;
    #pragma unroll
    for (int p = 0; p < TILE / 2; ++p)
        if (p < npairs)
            pair_rows(tb + 2 * p * RSTR, cS, cR, bS, bR,
                      xj[2 * p][0], xj[2 * p][1], xj[2 * p + 1][0], xj[2 * p + 1][1], acc);
}

__global__ __launch_bounds__(512, 2) void gather3_kernel(
    const float* __restrict__ nf,
    const float* __restrict__ Ws2, const float* __restrict__ bs2,
    const float* __restrict__ Wr2, const float* __restrict__ br2)
{
    extern __shared__ float lds[];

    // Stage Ws2/Wr2 transposed into LDS: column col at lds[mat*WMATF + col*36],
    // 36-float stride => bank rotation => even-spread b128 reads.
    for (int idx = threadIdx.x; idx < 2 * WND; idx += 512) {
        int mat = idx >= WND ? 1 : 0;
        int col = mat ? idx - WND : idx;
        const float* src = mat ? Wr2 : Ws2;
        float* dc = lds + mat * WMATF + col * WCOLS;
        #pragma unroll
        for (int j4 = 0; j4 < 8; ++j4) {
            float4 v = make_float4(src[(j4 * 4 + 0) * WND + col],
                                   src[(j4 * 4 + 1) * WND + col],
                                   src[(j4 * 4 + 2) * WND + col],
                                   src[(j4 * 4 + 3) * WND + col]);
            *reinterpret_cast<float4*>(dc + j4 * 4) = v;
        }
    }
    __syncthreads();

    int wv = threadIdx.x >> 6, l = threadIdx.x & 63;
    float* tb0 = lds + 2 * WMATF + wv * 2 * TILEF;
    float* tb1 = tb0 + TILEF;

    const float* cS[3][2];
    const float* cR[3][2];
    float bS[3][2], bR[3][2];
    #pragma unroll
    for (int m = 0; m < 3; ++m)
        #pragma unroll
        for (int q = 0; q < 2; ++q) {
            int col = m * CC + l + 64 * q;
            cS[m][q] = lds + col * WCOLS;
            cR[m][q] = lds + WMATF + col * WCOLS;
            bS[m][q] = bs2[col];
            bR[m][q] = br2[col];
        }

    int gw = blockIdx.x * GW + wv;
    for (int n = gw; n < NN; n += gridDim.x * GW) {
        int beg = g_offs[n], end = g_offs[n + 1];
        float acc[9][2] = {};

        float4 rawA[3], rawB[3];
        float xjA[TILE][2], xjB[TILE][2];
        tile_load(beg, end, l, nf, rawA, xjA);

        for (int t0 = beg; t0 < end; t0 += 2 * TILE) {
            tile_store_lds(tb0, l, rawA);
            tile_load(t0 + TILE, end, l, nf, rawB, xjB);      // prefetch (overlaps compute)
            tile_compute(tb0, min(TILE, end - t0), cS, cR, bS, bR, xjA, acc);
            if (t0 + TILE < end) {
                tile_store_lds(tb1, l, rawB);
                tile_load(t0 + 2 * TILE, end, l, nf, rawA, xjA);
                tile_compute(tb1, min(TILE, end - (t0 + TILE)), cS, cR, bS, bR, xjB, acc);
            }
        }

        float* A = g_accu + (size_t)n * MROW;
        #pragma unroll
        for (int m = 0; m < 9; ++m) {
            A[m * CC + l]      = acc[m][0];
            A[m * CC + 64 + l] = acc[m][1];
        }
    }
}

// Node-wise linear, 2 nodes per block.
__global__ __launch_bounds__(256) void lin2_kernel(
    const float* __restrict__ W0, const float* __restrict__ b0,
    const float* __restrict__ W1, const float* __restrict__ W2,
    float* __restrict__ out)
{
    __shared__ float sA[2 * MROW];
    int n0 = blockIdx.x * 2;
    const float4* g = reinterpret_cast<const float4*>(g_accu + (size_t)n0 * MROW);
    for (int i = threadIdx.x; i < 2 * MROW / 4; i += 256)
        reinterpret_cast<float4*>(sA)[i] = g[i];
    __syncthreads();

    int d  = threadIdx.x & (CC - 1);
    int nl = threadIdx.x >> 7;
    const float* a = sA + nl * MROW;

    float acc[9];
    #pragma unroll
    for (int m = 0; m < 9; ++m) acc[m] = 0.f;

    #pragma unroll 2
    for (int cc = 0; cc < CC; ++cc) {
        float w0 = W0[cc * CC + d];
        float w1 = W1[cc * CC + d];
        float w2 = W2[cc * CC + d];
        acc[0] = fmaf(a[cc],           w0, acc[0]);
        acc[1] = fmaf(a[CC + cc],      w1, acc[1]);
        acc[2] = fmaf(a[2 * CC + cc],  w1, acc[2]);
        acc[3] = fmaf(a[3 * CC + cc],  w1, acc[3]);
        acc[4] = fmaf(a[4 * CC + cc],  w2, acc[4]);
        acc[5] = fmaf(a[5 * CC + cc],  w2, acc[5]);
        acc[6] = fmaf(a[6 * CC + cc],  w2, acc[6]);
        acc[7] = fmaf(a[7 * CC + cc],  w2, acc[7]);
        acc[8] = fmaf(a[8 * CC + cc],  w2, acc[8]);
    }

    const float inv = 0.08838834764831845f;  // 1/sqrt(128)
    size_t ob = (size_t)(n0 + nl) * MROW;
    out[ob + d] = acc[0] * inv + b0[d];
    #pragma unroll
    for (int m = 0; m < 3; ++m) out[ob + CC + d * 3 + m]     = acc[1 + m] * inv;
    #pragma unroll
    for (int m = 0; m < 5; ++m) out[ob + 4 * CC + d * 5 + m] = acc[4 + m] * inv;
}

extern "C" void kernel_launch(void* const* d_in, const int* in_sizes, int n_in,
                              void* d_out, int out_size, void* d_ws, size_t ws_size,
                              hipStream_t stream)
{
    const float* node_feat  = (const float*)d_in[0];
    const float* edge_attr  = (const float*)d_in[1];
    const float* edge_rsh   = (const float*)d_in[2];
    const int*   edge_index = (const int*)  d_in[3];
    const float* Ws1 = (const float*)d_in[4];
    const float* bs1 = (const float*)d_in[5];
    const float* Ws2 = (const float*)d_in[6];
    const float* bs2 = (const float*)d_in[7];
    const float* Wr1 = (const float*)d_in[8];
    const float* br1 = (const float*)d_in[9];
    const float* Wr2 = (const float*)d_in[10];
    const float* br2 = (const float*)d_in[11];
    const float* W0  = (const float*)d_in[12];
    const float* b0  = (const float*)d_in[13];
    const float* W1  = (const float*)d_in[14];
    const float* W2  = (const float*)d_in[15];
    float* out = (float*)d_out;

    const int ldsBytes = (2 * WMATF + GW * 2 * TILEF) * 4;   // 149504 B
    hipFuncSetAttribute(reinterpret_cast<const void*>(gather3_kernel),
                        hipFuncAttributeMaxDynamicSharedMemorySize, ldsBytes);

    zero_deg_kernel<<<(NN + 255) / 256, 256, 0, stream>>>();
    hist_kernel<<<EE / 256, 256, 0, stream>>>(edge_index);
    scan_kernel<<<1, 1024, 0, stream>>>();
    mlp1_kernel<<<EE / 128, 128, 0, stream>>>(
        node_feat, edge_attr, edge_rsh, edge_index, Ws1, bs1, Wr1, br1);
    gather3_kernel<<<256, 512, ldsBytes, stream>>>(node_feat, Ws2, bs2, Wr2, br2);
    lin2_kernel<<<NN / 2, 256, 0, stream>>>(W0, b0, W1, W2, out);
}